// Round 6
// baseline (706.938 us; speedup 1.0000x reference)
//
#include <hip/hip_runtime.h>
#include <hip/hip_bf16.h>

// SpikeFP32Embedding: out[b,s,e,bit] = weight_pulse[token_ids[b,s], e, bit]
// token_ids: [8, 2048] int32  (in_sizes[0] = 16384)
// weight_pulse: [32768, 128, 32] float32 (rows of 4096 f32 = 16 KiB = 1024 x 16B)
// out: [8, 2048, 128, 32] float32
//
// Pure row gather, memory-bound. 256 MiB read + 256 MiB write -> ~85 us at
// 6.3 TB/s achievable. Strategy:
//  - 8 tokens per block, grid = 16384/8 = 2048 blocks (8 blocks/CU).
//  - Per inner iteration: batch-load 2 tokens' worth (8x 16B/lane) into
//    registers BEFORE any store -> 8 outstanding dwordx4 loads per lane,
//    no load->store round-trip serialization.
//  - Nontemporal stores: out is never re-read; don't pollute L2/L3 so the
//    cache capacity serves duplicate-token row re-reads instead.
//  - Token-id loads are block-uniform -> scalar loads (L2-hot, 64 KiB total).
//
// NOTE: __builtin_nontemporal_store requires a clang vector type, not HIP's
// float4 class -> use ext_vector_type(4) float.

typedef float v4f __attribute__((ext_vector_type(4)));

#define TOK_PER_BLOCK 8

__global__ __launch_bounds__(256) void spike_embed_gather(
    const int* __restrict__ tok,
    const v4f* __restrict__ w,
    v4f* __restrict__ out)
{
    const int base = blockIdx.x * TOK_PER_BLOCK;
    const int i = threadIdx.x;

#pragma unroll
    for (int j = 0; j < TOK_PER_BLOCK; j += 2) {
        const int r0 = tok[base + j];
        const int r1 = tok[base + j + 1];
        const v4f* __restrict__ s0 = w + (size_t)r0 * 1024;
        const v4f* __restrict__ s1 = w + (size_t)r1 * 1024;

        v4f v[8];
#pragma unroll
        for (int k = 0; k < 4; ++k) v[k]     = s0[i + k * 256];
#pragma unroll
        for (int k = 0; k < 4; ++k) v[4 + k] = s1[i + k * 256];

        v4f* __restrict__ d0 = out + (size_t)(base + j) * 1024;
        v4f* __restrict__ d1 = out + (size_t)(base + j + 1) * 1024;
#pragma unroll
        for (int k = 0; k < 4; ++k) __builtin_nontemporal_store(v[k],     &d0[i + k * 256]);
#pragma unroll
        for (int k = 0; k < 4; ++k) __builtin_nontemporal_store(v[4 + k], &d1[i + k * 256]);
    }
}

extern "C" void kernel_launch(void* const* d_in, const int* in_sizes, int n_in,
                              void* d_out, int out_size, void* d_ws, size_t ws_size,
                              hipStream_t stream) {
    const int* tok = (const int*)d_in[0];
    const v4f* w = (const v4f*)d_in[1];
    v4f* out = (v4f*)d_out;
    const int n_tokens = in_sizes[0];                       // 16384
    const int n_blocks = (n_tokens + TOK_PER_BLOCK - 1) / TOK_PER_BLOCK;  // 2048
    spike_embed_gather<<<n_blocks, 256, 0, stream>>>(tok, w, out);
}